// Round 2
// baseline (364.214 us; speedup 1.0000x reference)
//
#include <hip/hip_runtime.h>

// LaterallyConnectedLayer: B=16, NUM_FM=64, N=4, NF=256, H=W=32, KS=5. All fp32.
// Derived math:
//   w1[o][i]   = minmax5x5( K[i][o] )
//   wsum[o][g] = sum_n w1[o][64n+g]
//   L1[b,o]    = (1/64) * sum_g conv_same(A[b,g], wsum[o,g]) * S[o]
//   score[b,o] = (sumL1 - 1024*minL1)/(maxL1-minL1), 0 if degenerate
//                (the 0.9*A term of the reference score is constant across the
//                 4 multiplex candidates of a feature map -> drops from argmax)
//   n*[b,f]    = argmax_n score[b, 64n+f]     (first-max ties)
//   out[b,f]   = (1/64) * sum_g conv_same(A[b,g], w1[64n*_f+f, 64n*_g+g])
//                (diagonal zeroing of K only affects inactive input channels,
//                 which are zeroed in tmp_A anyway -> weights reduce to w1)

#define NFM 64
#define NMX 4
#define NFC 256
#define HW 1024
#define KK 25
#define WPAD 28   // padded per-map stride in wlds (floats); 28*4B = 112B, 16B-aligned

// --- Kernel 1: L1 stats -> score[b*256+o] -----------------------------------
// grid (64, 16): blockIdx.x -> group of 4 o's (one per wave), blockIdx.y = b.
// Prologue: each thread normalizes+sums the 4 multiplex maps for one (o_local,g)
// into LDS. Main loop: A channel staged in 36x36 LDS; each lane owns a 4x4
// output tile; weights broadcast-read from LDS (wave-uniform address).
__global__ __launch_bounds__(256) void kscore(const float* __restrict__ A,
                                              const float* __restrict__ K,
                                              const float* __restrict__ S,
                                              float* __restrict__ score) {
    __shared__ float wlds[4 * NFM * WPAD];   // 28672 B
    __shared__ float pa[36 * 36];            // 5184 B
    int t = threadIdx.x;
    int b = blockIdx.y;

    {   // prologue: wsum[o_local][g][0..24]
        int ol = t & 3, g = t >> 2;
        int o = blockIdx.x * 4 + ol;
        float w[KK];
#pragma unroll
        for (int k = 0; k < KK; ++k) w[k] = 0.f;
#pragma unroll
        for (int n = 0; n < NMX; ++n) {
            const float* src = K + ((n * NFM + g) * NFC + o) * KK;  // K[64n+g][o]
            float v[KK];
            float mn = 1e30f, mx = -1e30f;
#pragma unroll
            for (int k = 0; k < KK; ++k) {
                v[k] = src[k];
                mn = fminf(mn, v[k]);
                mx = fmaxf(mx, v[k]);
            }
            float d = mx - mn;
            float r = d > 0.f ? 1.f / d : 0.f;
#pragma unroll
            for (int k = 0; k < KK; ++k) w[k] += (v[k] - mn) * r;
        }
        float* dst = &wlds[(ol * NFM + g) * WPAD];
#pragma unroll
        for (int k = 0; k < KK; ++k) dst[k] = w[k];
    }
    for (int idx = t; idx < 36 * 36; idx += 256) pa[idx] = 0.f;
    __syncthreads();

    int wv = __builtin_amdgcn_readfirstlane(t >> 6);
    int lane = t & 63;
    int o = blockIdx.x * 4 + wv;
    int xb = (lane & 7) * 4;
    int yb = (lane >> 3) * 4;

    float acc[16];
#pragma unroll
    for (int j = 0; j < 16; ++j) acc[j] = 0.f;

    const float* Ab = A + b * NFM * HW;

    for (int g = 0; g < NFM; ++g) {
        {   // stage A[b,g] interior (border stays zero)
            float4 q = ((const float4*)(Ab + g * HW))[t];
            int row = t >> 3, col = (t & 7) * 4;
            float* d = &pa[(row + 2) * 36 + col + 2];
            d[0] = q.x; d[1] = q.y; d[2] = q.z; d[3] = q.w;
        }
        __syncthreads();

        const float* wg = &wlds[(wv * NFM + g) * WPAD];  // wave-uniform -> broadcast
        float wr[KK];
#pragma unroll
        for (int k = 0; k < KK; ++k) wr[k] = wg[k];

#pragma unroll
        for (int r = 0; r < 8; ++r) {
            float4 a0 = *(const float4*)&pa[(yb + r) * 36 + xb];
            float4 a1 = *(const float4*)&pa[(yb + r) * 36 + xb + 4];
            float a[8] = {a0.x, a0.y, a0.z, a0.w, a1.x, a1.y, a1.z, a1.w};
#pragma unroll
            for (int py = 0; py < 4; ++py) {
                int u = r - py;
                if (u >= 0 && u < 5) {
#pragma unroll
                    for (int v = 0; v < 5; ++v) {
                        float wvv = wr[u * 5 + v];
#pragma unroll
                        for (int px = 0; px < 4; ++px)
                            acc[py * 4 + px] = fmaf(a[px + v], wvv, acc[py * 4 + px]);
                    }
                }
            }
        }
        __syncthreads();
    }

    float scale = S[o] * (1.f / 64.f);
    float lmn = 1e30f, lmx = -1e30f, lsum = 0.f;
#pragma unroll
    for (int j = 0; j < 16; ++j) {
        float vv = acc[j] * scale;
        lmn = fminf(lmn, vv);
        lmx = fmaxf(lmx, vv);
        lsum += vv;
    }
#pragma unroll
    for (int m = 1; m < 64; m <<= 1) {
        lmn = fminf(lmn, __shfl_xor(lmn, m, 64));
        lmx = fmaxf(lmx, __shfl_xor(lmx, m, 64));
        lsum += __shfl_xor(lsum, m, 64);
    }
    if (lane == 0) {
        float d = lmx - lmn;
        score[b * NFC + o] = d > 0.f ? (lsum - 1024.f * lmn) / d : 0.f;
    }
}

// --- Kernel 2: argmax over multiplex ----------------------------------------
__global__ void kargmax(const float* __restrict__ score, int* __restrict__ amax) {
    int t = blockIdx.x * blockDim.x + threadIdx.x;
    if (t >= 16 * NFM) return;
    int b = t >> 6, f = t & 63;
    const float* s = score + b * NFC;
    float best = s[f];
    int bi = 0;
#pragma unroll
    for (int n = 1; n < NMX; ++n) {
        float v = s[n * NFM + f];
        if (v > best) { best = v; bi = n; }   // first-max tie semantics
    }
    amax[t] = bi;
}

// --- Kernel 3: final gathered conv -> out -----------------------------------
// grid (16, 16): blockIdx.x -> group of 4 f's (one per wave), blockIdx.y = b.
__global__ __launch_bounds__(256) void kout(const float* __restrict__ A,
                                            const float* __restrict__ K,
                                            const int* __restrict__ amax,
                                            float* __restrict__ out) {
    __shared__ float wlds[4 * NFM * WPAD];
    __shared__ float pa[36 * 36];
    int t = threadIdx.x;
    int b = blockIdx.y;
    const int* am = amax + b * NFM;

    {   // prologue: w1[o_f][ig] for this block's 4 f's, one (f_local,g) per thread
        int fl = t & 3, g = t >> 2;
        int f = blockIdx.x * 4 + fl;
        int o = am[f] * NFM + f;     // gathered output channel
        int ig = am[g] * NFM + g;    // active input channel for fm g
        const float* src = K + (ig * NFC + o) * KK;  // K[ig][o]
        float v[KK];
        float mn = 1e30f, mx = -1e30f;
#pragma unroll
        for (int k = 0; k < KK; ++k) {
            v[k] = src[k];
            mn = fminf(mn, v[k]);
            mx = fmaxf(mx, v[k]);
        }
        float d = mx - mn;
        float r = d > 0.f ? 1.f / d : 0.f;
        float* dst = &wlds[(fl * NFM + g) * WPAD];
#pragma unroll
        for (int k = 0; k < KK; ++k) dst[k] = (v[k] - mn) * r;
    }
    for (int idx = t; idx < 36 * 36; idx += 256) pa[idx] = 0.f;
    __syncthreads();

    int wv = __builtin_amdgcn_readfirstlane(t >> 6);
    int lane = t & 63;
    int f = blockIdx.x * 4 + wv;
    int xb = (lane & 7) * 4;
    int yb = (lane >> 3) * 4;

    float acc[16];
#pragma unroll
    for (int j = 0; j < 16; ++j) acc[j] = 0.f;

    const float* Ab = A + b * NFM * HW;

    for (int g = 0; g < NFM; ++g) {
        {
            float4 q = ((const float4*)(Ab + g * HW))[t];
            int row = t >> 3, col = (t & 7) * 4;
            float* d = &pa[(row + 2) * 36 + col + 2];
            d[0] = q.x; d[1] = q.y; d[2] = q.z; d[3] = q.w;
        }
        __syncthreads();

        const float* wg = &wlds[(wv * NFM + g) * WPAD];
        float wr[KK];
#pragma unroll
        for (int k = 0; k < KK; ++k) wr[k] = wg[k];

#pragma unroll
        for (int r = 0; r < 8; ++r) {
            float4 a0 = *(const float4*)&pa[(yb + r) * 36 + xb];
            float4 a1 = *(const float4*)&pa[(yb + r) * 36 + xb + 4];
            float a[8] = {a0.x, a0.y, a0.z, a0.w, a1.x, a1.y, a1.z, a1.w};
#pragma unroll
            for (int py = 0; py < 4; ++py) {
                int u = r - py;
                if (u >= 0 && u < 5) {
#pragma unroll
                    for (int v = 0; v < 5; ++v) {
                        float wvv = wr[u * 5 + v];
#pragma unroll
                        for (int px = 0; px < 4; ++px)
                            acc[py * 4 + px] = fmaf(a[px + v], wvv, acc[py * 4 + px]);
                    }
                }
            }
        }
        __syncthreads();
    }

    float* ob = out + (b * NFM + f) * HW;
#pragma unroll
    for (int py = 0; py < 4; ++py) {
        float4 q;
        q.x = acc[py * 4 + 0] * (1.f / 64.f);
        q.y = acc[py * 4 + 1] * (1.f / 64.f);
        q.z = acc[py * 4 + 2] * (1.f / 64.f);
        q.w = acc[py * 4 + 3] * (1.f / 64.f);
        *(float4*)&ob[(yb + py) * 32 + xb] = q;
    }
}

extern "C" void kernel_launch(void* const* d_in, const int* in_sizes, int n_in,
                              void* d_out, int out_size, void* d_ws, size_t ws_size,
                              hipStream_t stream) {
    const float* A = (const float*)d_in[0];   // (16,64,32,32) f32
    const float* K = (const float*)d_in[1];   // (256,256,5,5) f32
    const float* S = (const float*)d_in[2];   // (256,) f32
    float* out = (float*)d_out;               // (16,64,32,32) f32

    char* ws = (char*)d_ws;
    float* score = (float*)ws;                // 16*256*4 = 16384 B
    int*   amax  = (int*)(ws + 16384);        // 16*64*4  =  4096 B

    kscore<<<dim3(64, 16), dim3(256), 0, stream>>>(A, K, S, score);
    kargmax<<<dim3(4), dim3(256), 0, stream>>>(score, amax);
    kout<<<dim3(16, 16), dim3(256), 0, stream>>>(A, K, amax, out);
}

// Round 3
// 333.145 us; speedup vs baseline: 1.0933x; 1.0933x over previous
//
#include <hip/hip_runtime.h>

// LaterallyConnectedLayer: B=16, NUM_FM=64, N=4, NF=256, H=W=32, KS=5. All fp32.
// Derived math:
//   w1[o][i]   = minmax5x5( K[i][o] )
//   wsum[o][g] = sum_n w1[o][64n+g]
//   score[b,o] = (sum-1024*min)/(max-min) over conv_same(A[b,:], wsum[o,:])*S[o]
//   n*[b,f]    = argmax_n score[b,64n+f]  (first-max ties; constant A-term drops)
//   out[b,f]   = (1/64) sum_g conv_same(A[b,g], w1[64n*_f+f, 64n*_g+g])

#define NFM 64
#define NMX 4
#define NFC 256
#define HW 1024
#define KK 25

// --- kw1: w1[o][i][k] = minmax-normalized K[i][o][k] ------------------------
__global__ __launch_bounds__(256) void kw1(const float* __restrict__ K,
                                           float* __restrict__ w1) {
    int i = blockIdx.x, o = threadIdx.x;
    const float* src = K + (i * NFC + o) * KK;
    float v[KK];
    float mn = 1e30f, mx = -1e30f;
#pragma unroll
    for (int k = 0; k < KK; ++k) {
        v[k] = src[k];
        mn = fminf(mn, v[k]);
        mx = fmaxf(mx, v[k]);
    }
    float d = mx - mn;
    float r = d > 0.f ? 1.f / d : 0.f;
    float* dst = w1 + (o * NFC + i) * KK;
#pragma unroll
    for (int k = 0; k < KK; ++k) dst[k] = (v[k] - mn) * r;
}

// --- kws: wsum[o][g][k] = sum_n w1[o][64n+g][k] -----------------------------
__global__ __launch_bounds__(64) void kws(const float* __restrict__ w1,
                                          float* __restrict__ wsum) {
    int o = blockIdx.x, g = threadIdx.x;
    float s[KK];
#pragma unroll
    for (int k = 0; k < KK; ++k) s[k] = 0.f;
#pragma unroll
    for (int n = 0; n < NMX; ++n) {
        const float* src = w1 + (o * NFC + n * NFM + g) * KK;
#pragma unroll
        for (int k = 0; k < KK; ++k) s[k] += src[k];
    }
    float* dst = wsum + (o * NFM + g) * KK;
#pragma unroll
    for (int k = 0; k < KK; ++k) dst[k] = s[k];
}

// --- kscore: L1 stats -> score[b*256+o] -------------------------------------
// grid (64,16), 256 thr. One o per wave. Double-buffered 36x36 LDS A-tile,
// weights via wave-uniform scalar loads from global wsum.
__global__ __launch_bounds__(256) void kscore(const float* __restrict__ A,
                                              const float* __restrict__ wsum,
                                              const float* __restrict__ S,
                                              float* __restrict__ score) {
    __shared__ float pa[2][36 * 36];
    int t = threadIdx.x, b = blockIdx.y;
    int wv = __builtin_amdgcn_readfirstlane(t >> 6);
    int lane = t & 63;
    int o = blockIdx.x * 4 + wv;
    int xb = (lane & 7) * 4;
    int yb = (lane >> 3) * 4;

    for (int idx = t; idx < 2 * 36 * 36; idx += 256) ((float*)pa)[idx] = 0.f;

    const float* Ab = A + b * NFM * HW;
    int srow = t >> 3, scol = (t & 7) * 4;
    float* wp0 = &pa[0][(srow + 2) * 36 + scol + 2];
    float* wp1 = &pa[1][(srow + 2) * 36 + scol + 2];

    __syncthreads();
    {   // stage g=0 into buf0 (float2 writes -> ds_write_b64, low conflict)
        float4 q = ((const float4*)Ab)[t];
        *(float2*)&wp0[0] = make_float2(q.x, q.y);
        *(float2*)&wp0[2] = make_float2(q.z, q.w);
    }
    __syncthreads();

    float acc[16];
#pragma unroll
    for (int j = 0; j < 16; ++j) acc[j] = 0.f;

    for (int g = 0; g < NFM; ++g) {
        float4 qn;
        bool more = (g + 1) < NFM;
        if (more) qn = ((const float4*)(Ab + (g + 1) * HW))[t];

        const float* wg = wsum + (o * NFM + g) * KK;   // SGPR address -> s_load
        float wr[KK];
#pragma unroll
        for (int k = 0; k < KK; ++k) wr[k] = wg[k];

        const float* buf = pa[g & 1];
#pragma unroll
        for (int r = 0; r < 8; ++r) {
            float4 a0 = *(const float4*)&buf[(yb + r) * 36 + xb];
            float4 a1 = *(const float4*)&buf[(yb + r) * 36 + xb + 4];
            float a[8] = {a0.x, a0.y, a0.z, a0.w, a1.x, a1.y, a1.z, a1.w};
#pragma unroll
            for (int py = 0; py < 4; ++py) {
                int u = r - py;
                if (u >= 0 && u < 5) {
#pragma unroll
                    for (int v = 0; v < 5; ++v) {
                        float wvv = wr[u * 5 + v];
#pragma unroll
                        for (int px = 0; px < 4; ++px)
                            acc[py * 4 + px] = fmaf(a[px + v], wvv, acc[py * 4 + px]);
                    }
                }
            }
        }
        if (more) {
            float* wp = (g & 1) ? wp0 : wp1;   // buf[(g+1)&1]
            *(float2*)&wp[0] = make_float2(qn.x, qn.y);
            *(float2*)&wp[2] = make_float2(qn.z, qn.w);
        }
        __syncthreads();
    }

    float scale = S[o] * (1.f / 64.f);
    float lmn = 1e30f, lmx = -1e30f, lsum = 0.f;
#pragma unroll
    for (int j = 0; j < 16; ++j) {
        float vv = acc[j] * scale;
        lmn = fminf(lmn, vv);
        lmx = fmaxf(lmx, vv);
        lsum += vv;
    }
#pragma unroll
    for (int m = 1; m < 64; m <<= 1) {
        lmn = fminf(lmn, __shfl_xor(lmn, m, 64));
        lmx = fmaxf(lmx, __shfl_xor(lmx, m, 64));
        lsum += __shfl_xor(lsum, m, 64);
    }
    if (lane == 0) {
        float d = lmx - lmn;
        score[b * NFC + o] = d > 0.f ? (lsum - 1024.f * lmn) / d : 0.f;
    }
}

// --- kargmax ----------------------------------------------------------------
__global__ void kargmax(const float* __restrict__ score, int* __restrict__ amax) {
    int t = blockIdx.x * blockDim.x + threadIdx.x;
    if (t >= 16 * NFM) return;
    int b = t >> 6, f = t & 63;
    const float* s = score + b * NFC;
    float best = s[f];
    int bi = 0;
#pragma unroll
    for (int n = 1; n < NMX; ++n) {
        float v = s[n * NFM + f];
        if (v > best) { best = v; bi = n; }
    }
    amax[t] = bi;
}

// --- kout: gathered conv -> out ---------------------------------------------
// grid (16, 2, 16): x = f-group of 4, y = spatial half (16 rows), z = b.
// Per wave: one f, lanes tile the 32x16 half with 4x2 tiles.
__global__ __launch_bounds__(256) void kout(const float* __restrict__ A,
                                            const float* __restrict__ w1,
                                            const int* __restrict__ amax,
                                            float* __restrict__ out) {
    __shared__ float pa[2][20 * 36];
    int t = threadIdx.x, z = blockIdx.y, b = blockIdx.z;
    const int* am = amax + b * NFM;
    int wv = __builtin_amdgcn_readfirstlane(t >> 6);
    int lane = t & 63;
    int f = blockIdx.x * 4 + wv;
    int o = am[f] * NFM + f;                 // wave-uniform
    int y0 = z * 16;
    int xb = (lane & 7) * 4;
    int yb = (lane >> 3) * 2;                // 0..14

    for (int idx = t; idx < 2 * 20 * 36; idx += 256) ((float*)pa)[idx] = 0.f;

    const float* Ab = A + b * NFM * HW;
    // staging: threads 0..159 each load one float4 of rows y0-2..y0+17
    int lrow = t >> 3, c4 = (t & 7) * 4;
    int gy = y0 - 2 + lrow;
    bool sactive = (t < 160);
    bool inrange = sactive && (gy >= 0) && (gy < 32);
    float* sp0 = &pa[0][lrow * 36 + c4 + 2];
    float* sp1 = &pa[1][lrow * 36 + c4 + 2];

    __syncthreads();
    if (sactive) {
        float4 q = make_float4(0.f, 0.f, 0.f, 0.f);
        if (inrange) q = *(const float4*)(Ab + gy * 32 + c4);
        *(float2*)&sp0[0] = make_float2(q.x, q.y);
        *(float2*)&sp0[2] = make_float2(q.z, q.w);
    }
    __syncthreads();

    float acc[8];
#pragma unroll
    for (int j = 0; j < 8; ++j) acc[j] = 0.f;

    for (int g = 0; g < NFM; ++g) {
        float4 qn = make_float4(0.f, 0.f, 0.f, 0.f);
        bool more = (g + 1) < NFM;
        if (more && inrange) qn = *(const float4*)(Ab + (g + 1) * HW + gy * 32 + c4);

        int ig = am[g] * NFM + g;                        // wave-uniform
        const float* wg = w1 + (o * NFC + ig) * KK;      // SGPR address
        float wr[KK];
#pragma unroll
        for (int k = 0; k < KK; ++k) wr[k] = wg[k];

        const float* buf = pa[g & 1];
#pragma unroll
        for (int r = 0; r < 6; ++r) {
            float4 a0 = *(const float4*)&buf[(yb + r) * 36 + xb];
            float4 a1 = *(const float4*)&buf[(yb + r) * 36 + xb + 4];
            float a[8] = {a0.x, a0.y, a0.z, a0.w, a1.x, a1.y, a1.z, a1.w};
#pragma unroll
            for (int py = 0; py < 2; ++py) {
                int u = r - py;
                if (u >= 0 && u < 5) {
#pragma unroll
                    for (int v = 0; v < 5; ++v) {
                        float wvv = wr[u * 5 + v];
#pragma unroll
                        for (int px = 0; px < 4; ++px)
                            acc[py * 4 + px] = fmaf(a[px + v], wvv, acc[py * 4 + px]);
                    }
                }
            }
        }
        if (more && sactive) {
            float* sp = (g & 1) ? sp0 : sp1;
            *(float2*)&sp[0] = make_float2(qn.x, qn.y);
            *(float2*)&sp[2] = make_float2(qn.z, qn.w);
        }
        __syncthreads();
    }

    float* ob = out + (b * NFM + f) * HW;
#pragma unroll
    for (int py = 0; py < 2; ++py) {
        float4 q;
        q.x = acc[py * 4 + 0] * (1.f / 64.f);
        q.y = acc[py * 4 + 1] * (1.f / 64.f);
        q.z = acc[py * 4 + 2] * (1.f / 64.f);
        q.w = acc[py * 4 + 3] * (1.f / 64.f);
        *(float4*)&ob[(y0 + yb + py) * 32 + xb] = q;
    }
}

extern "C" void kernel_launch(void* const* d_in, const int* in_sizes, int n_in,
                              void* d_out, int out_size, void* d_ws, size_t ws_size,
                              hipStream_t stream) {
    const float* A = (const float*)d_in[0];   // (16,64,32,32) f32
    const float* K = (const float*)d_in[1];   // (256,256,5,5) f32
    const float* S = (const float*)d_in[2];   // (256,) f32
    float* out = (float*)d_out;               // (16,64,32,32) f32

    char* ws = (char*)d_ws;
    float* w1    = (float*)ws;                               // 6,553,600 B
    float* wsum  = (float*)(ws + 6553600);                   // 1,638,400 B
    float* score = (float*)(ws + 6553600 + 1638400);         // 16,384 B
    int*   amax  = (int*)  (ws + 6553600 + 1638400 + 16384); // 4,096 B

    kw1<<<dim3(NFC), dim3(NFC), 0, stream>>>(K, w1);
    kws<<<dim3(NFC), dim3(NFM), 0, stream>>>(w1, wsum);
    kscore<<<dim3(64, 16), dim3(256), 0, stream>>>(A, wsum, S, score);
    kargmax<<<dim3(4), dim3(256), 0, stream>>>(score, amax);
    kout<<<dim3(16, 2, 16), dim3(256), 0, stream>>>(A, w1, amax, out);
}

// Round 4
// 320.373 us; speedup vs baseline: 1.1368x; 1.0399x over previous
//
#include <hip/hip_runtime.h>

// LaterallyConnectedLayer: B=16, NUM_FM=64, N=4, NF=256, H=W=32, KS=5. All fp32.
// Derived math:
//   w1t[i][o][k]  = minmax5x5( K[i][o] )                (i-major layout)
//   wsum2[g][o][k]= sum_n w1t[64n+g][o][k]
//   score[b,o]    = (sum-1024*min)/(max-min) over conv_same(A[b,:],wsum[o,:])*S[o]
//   n*[b,f]       = argmax_n score[b,64n+f]  (first-max ties; const A-term drops)
//   out[b,f]      = (1/64) sum_g conv_same(A[b,g], w1[64n*_f+f][64n*_g+g])

#define NFM 64
#define NMX 4
#define NFC 256
#define HW 1024
#define KK 25

// --- kprep: normalize K -> w1t (coalesced), accumulate wsum2 ----------------
// grid 256 = (g 0..63) x (o-quarter 0..3), 256 threads.
__global__ __launch_bounds__(256) void kprep(const float* __restrict__ K,
                                             float* __restrict__ w1t,
                                             float* __restrict__ wsum2) {
    __shared__ __align__(16) float buf[64 * KK];   // 1600 floats
    int g = blockIdx.x & 63, o0 = (blockIdx.x >> 6) * 64;
    int t = threadIdx.x;
    float wacc[KK];
#pragma unroll
    for (int k = 0; k < KK; ++k) wacc[k] = 0.f;

    for (int n = 0; n < NMX; ++n) {
        int i = n * NFM + g;
        const float4* src = (const float4*)(K + (i * NFC + o0) * KK);  // 400 f4
        __syncthreads();
        ((float4*)buf)[t] = src[t];
        if (t < 144) ((float4*)buf)[t + 256] = src[t + 256];
        __syncthreads();
        if (t < 64) {
            float v[KK];
            float mn = 1e30f, mx = -1e30f;
#pragma unroll
            for (int k = 0; k < KK; ++k) {
                v[k] = buf[t * KK + k];
                mn = fminf(mn, v[k]);
                mx = fmaxf(mx, v[k]);
            }
            float d = mx - mn;
            float r = d > 0.f ? 1.f / d : 0.f;
#pragma unroll
            for (int k = 0; k < KK; ++k) {
                float nv = (v[k] - mn) * r;
                buf[t * KK + k] = nv;
                wacc[k] += nv;
            }
        }
        __syncthreads();
        float4* dst = (float4*)(w1t + (i * NFC + o0) * KK);
        dst[t] = ((float4*)buf)[t];
        if (t < 144) dst[t + 256] = ((float4*)buf)[t + 256];
    }
    __syncthreads();
    if (t < 64) {
#pragma unroll
        for (int k = 0; k < KK; ++k) buf[t * KK + k] = wacc[k];
    }
    __syncthreads();
    float4* dst = (float4*)(wsum2 + (g * NFC + o0) * KK);
    dst[t] = ((float4*)buf)[t];
    if (t < 144) dst[t + 256] = ((float4*)buf)[t + 256];
}

// --- kscore: grid (32,16), 256 thr. Wave = o-PAIR x full image --------------
// Lane: 4x4 pixel tile. 16 ds_read_b128 feed 800 FMAs per g (2 o's share reads).
__global__ __launch_bounds__(256) void kscore(const float* __restrict__ A,
                                              const float* __restrict__ wsum2,
                                              const float* __restrict__ S,
                                              float* __restrict__ score) {
    __shared__ __align__(16) float pa[2][36 * 36];
    int t = threadIdx.x, b = blockIdx.y;
    int wv = __builtin_amdgcn_readfirstlane(t >> 6);
    int lane = t & 63;
    int ob = blockIdx.x * 8 + wv * 2;          // o-pair base
    int xb = (lane & 7) * 4;
    int yb = (lane >> 3) * 4;

    for (int idx = t; idx < 2 * 36 * 36; idx += 256) ((float*)pa)[idx] = 0.f;

    const float* Ab = A + b * NFM * HW;
    float* wp0 = &pa[0][((t >> 3) + 2) * 36 + (t & 7) * 4 + 2];
    float* wp1 = &pa[1][((t >> 3) + 2) * 36 + (t & 7) * 4 + 2];

    __syncthreads();
    {
        float4 q = ((const float4*)Ab)[t];
        *(float2*)&wp0[0] = make_float2(q.x, q.y);
        *(float2*)&wp0[2] = make_float2(q.z, q.w);
    }
    __syncthreads();

    float acc0[16], acc1[16];
#pragma unroll
    for (int j = 0; j < 16; ++j) { acc0[j] = 0.f; acc1[j] = 0.f; }

    for (int g = 0; g < NFM; ++g) {
        float4 qn;
        bool more = (g + 1) < NFM;
        if (more) qn = ((const float4*)(Ab + (g + 1) * HW))[t];

        const float* wg = wsum2 + (g * NFC + ob) * KK;   // uniform -> s_load
        float w0[KK], w1r[KK];
#pragma unroll
        for (int k = 0; k < KK; ++k) { w0[k] = wg[k]; w1r[k] = wg[KK + k]; }

        const float* buf = pa[g & 1];
#pragma unroll
        for (int r = 0; r < 8; ++r) {
            float4 a0 = *(const float4*)&buf[(yb + r) * 36 + xb];
            float4 a1 = *(const float4*)&buf[(yb + r) * 36 + xb + 4];
            float a[8] = {a0.x, a0.y, a0.z, a0.w, a1.x, a1.y, a1.z, a1.w};
#pragma unroll
            for (int py = 0; py < 4; ++py) {
                int u = r - py;
                if (u >= 0 && u < 5) {
#pragma unroll
                    for (int v = 0; v < 5; ++v) {
                        float wa = w0[u * 5 + v], wb = w1r[u * 5 + v];
#pragma unroll
                        for (int px = 0; px < 4; ++px) {
                            acc0[py * 4 + px] = fmaf(a[px + v], wa, acc0[py * 4 + px]);
                            acc1[py * 4 + px] = fmaf(a[px + v], wb, acc1[py * 4 + px]);
                        }
                    }
                }
            }
        }
        if (more) {
            float* wp = (g & 1) ? wp0 : wp1;
            *(float2*)&wp[0] = make_float2(qn.x, qn.y);
            *(float2*)&wp[2] = make_float2(qn.z, qn.w);
        }
        __syncthreads();
    }

#pragma unroll
    for (int oo = 0; oo < 2; ++oo) {
        const float* ac = oo ? acc1 : acc0;
        float scale = S[ob + oo] * (1.f / 64.f);
        float lmn = 1e30f, lmx = -1e30f, lsum = 0.f;
#pragma unroll
        for (int j = 0; j < 16; ++j) {
            float vv = ac[j] * scale;
            lmn = fminf(lmn, vv);
            lmx = fmaxf(lmx, vv);
            lsum += vv;
        }
#pragma unroll
        for (int m = 1; m < 64; m <<= 1) {
            lmn = fminf(lmn, __shfl_xor(lmn, m, 64));
            lmx = fmaxf(lmx, __shfl_xor(lmx, m, 64));
            lsum += __shfl_xor(lsum, m, 64);
        }
        if (lane == 0) {
            float d = lmx - lmn;
            score[b * NFC + ob + oo] = d > 0.f ? (lsum - 1024.f * lmn) / d : 0.f;
        }
    }
}

// --- kout: grid (16,16), 256 thr. Argmax folded in; wave = 1 f x full image -
__global__ __launch_bounds__(256) void kout(const float* __restrict__ A,
                                            const float* __restrict__ w1t,
                                            const float* __restrict__ score,
                                            float* __restrict__ out) {
    __shared__ __align__(16) float pa[2][36 * 36];
    __shared__ float scl[NFC];
    __shared__ int igL[NFM];
    int t = threadIdx.x, b = blockIdx.y;
    int wv = __builtin_amdgcn_readfirstlane(t >> 6);
    int lane = t & 63;
    int f = blockIdx.x * 4 + wv;
    int xb = (lane & 7) * 4;
    int yb = (lane >> 3) * 4;

    scl[t] = score[b * NFC + t];
    for (int idx = t; idx < 2 * 36 * 36; idx += 256) ((float*)pa)[idx] = 0.f;
    __syncthreads();
    if (t < 64) {
        float best = scl[t];
        int bi = 0;
#pragma unroll
        for (int n = 1; n < NMX; ++n) {
            float v = scl[n * NFM + t];
            if (v > best) { best = v; bi = n; }
        }
        igL[t] = bi * NFM + t;   // active channel id for feature map t
    }
    __syncthreads();

    int o = __builtin_amdgcn_readfirstlane(igL[f]);   // gathered output channel

    const float* Ab = A + b * NFM * HW;
    float* wp0 = &pa[0][((t >> 3) + 2) * 36 + (t & 7) * 4 + 2];
    float* wp1 = &pa[1][((t >> 3) + 2) * 36 + (t & 7) * 4 + 2];
    {
        float4 q = ((const float4*)Ab)[t];
        *(float2*)&wp0[0] = make_float2(q.x, q.y);
        *(float2*)&wp0[2] = make_float2(q.z, q.w);
    }

    float acc[16];
#pragma unroll
    for (int j = 0; j < 16; ++j) acc[j] = 0.f;

    // weight software pipeline: wn holds g's weights entering iteration g
    int ig0 = __builtin_amdgcn_readfirstlane(igL[0]);
    float wn[KK];
    {
        const float* wp = w1t + (ig0 * NFC + o) * KK;
#pragma unroll
        for (int k = 0; k < KK; ++k) wn[k] = wp[k];
    }
    __syncthreads();

    for (int g = 0; g < NFM; ++g) {
        float4 qn;
        bool more = (g + 1) < NFM;
        if (more) qn = ((const float4*)(Ab + (g + 1) * HW))[t];

        float wc[KK];
#pragma unroll
        for (int k = 0; k < KK; ++k) wc[k] = wn[k];
        if (more) {
            int ign = __builtin_amdgcn_readfirstlane(igL[g + 1]);
            const float* wp = w1t + (ign * NFC + o) * KK;   // s_load during FMAs
#pragma unroll
            for (int k = 0; k < KK; ++k) wn[k] = wp[k];
        }

        const float* buf = pa[g & 1];
#pragma unroll
        for (int r = 0; r < 8; ++r) {
            float4 a0 = *(const float4*)&buf[(yb + r) * 36 + xb];
            float4 a1 = *(const float4*)&buf[(yb + r) * 36 + xb + 4];
            float a[8] = {a0.x, a0.y, a0.z, a0.w, a1.x, a1.y, a1.z, a1.w};
#pragma unroll
            for (int py = 0; py < 4; ++py) {
                int u = r - py;
                if (u >= 0 && u < 5) {
#pragma unroll
                    for (int v = 0; v < 5; ++v) {
                        float wvv = wc[u * 5 + v];
#pragma unroll
                        for (int px = 0; px < 4; ++px)
                            acc[py * 4 + px] = fmaf(a[px + v], wvv, acc[py * 4 + px]);
                    }
                }
            }
        }
        if (more) {
            float* wp = (g & 1) ? wp0 : wp1;
            *(float2*)&wp[0] = make_float2(qn.x, qn.y);
            *(float2*)&wp[2] = make_float2(qn.z, qn.w);
        }
        __syncthreads();
    }

    float* ob = out + (b * NFM + f) * HW;
#pragma unroll
    for (int py = 0; py < 4; ++py) {
        float4 q;
        q.x = acc[py * 4 + 0] * (1.f / 64.f);
        q.y = acc[py * 4 + 1] * (1.f / 64.f);
        q.z = acc[py * 4 + 2] * (1.f / 64.f);
        q.w = acc[py * 4 + 3] * (1.f / 64.f);
        *(float4*)&ob[(yb + py) * 32 + xb] = q;
    }
}

extern "C" void kernel_launch(void* const* d_in, const int* in_sizes, int n_in,
                              void* d_out, int out_size, void* d_ws, size_t ws_size,
                              hipStream_t stream) {
    const float* A = (const float*)d_in[0];   // (16,64,32,32) f32
    const float* K = (const float*)d_in[1];   // (256,256,5,5) f32
    const float* S = (const float*)d_in[2];   // (256,) f32
    float* out = (float*)d_out;               // (16,64,32,32) f32

    char* ws = (char*)d_ws;
    float* w1t   = (float*)ws;                        // 256*256*25*4 = 6,553,600 B
    float* wsum2 = (float*)(ws + 6553600);            // 64*256*25*4  = 1,638,400 B
    float* score = (float*)(ws + 6553600 + 1638400);  // 16,384 B

    kprep<<<dim3(256), dim3(256), 0, stream>>>(K, w1t, wsum2);
    kscore<<<dim3(32, 16), dim3(256), 0, stream>>>(A, wsum2, S, score);
    kout<<<dim3(16, 16), dim3(256), 0, stream>>>(A, w1t, score, out);
}